// Round 2
// baseline (21360.693 us; speedup 1.0000x reference)
//
#include <hip/hip_runtime.h>
#include <hip/hip_bf16.h>

typedef unsigned short u16;
typedef unsigned int u32;
typedef __attribute__((ext_vector_type(8))) short short8;
typedef __attribute__((ext_vector_type(4))) float floatx4;

#define MTOT 43520   // B*N = 512*85
#define DIMM 512
#define NHEAD 8

__device__ __forceinline__ float b2f(u16 u) { return __uint_as_float(((unsigned)u) << 16); }
__device__ __forceinline__ u16 f2b(float f) {
  unsigned u = __float_as_uint(f);
  return (u16)((u + 0x7FFFu + ((u >> 16) & 1u)) >> 16);  // RNE; inputs always finite
}

// async global->LDS, 16B per lane; lds base must be wave-uniform, data lands at base + lane*16
__device__ __forceinline__ void gld16(void* lds, const void* g) {
  __builtin_amdgcn_global_load_lds(
      (const __attribute__((address_space(1))) u32*)g,
      (__attribute__((address_space(3))) u32*)lds, 16, 0, 0);
}

// ---------------- transpose + fp32->bf16: W[K][N] f32 -> Wt[N][K] bf16, per layer z ----------------
__global__ __launch_bounds__(256) void transpose_conv(const float* __restrict__ in,
    u16* __restrict__ out, int K, int N)
{
  const float* W  = in  + (size_t)blockIdx.z * K * N;
  u16*         Wt = out + (size_t)blockIdx.z * K * N;
  int n0 = blockIdx.x * 64, k0 = blockIdx.y * 64;
  int t = threadIdx.x;
  #pragma unroll
  for (int i = 0; i < 2; i++) {
    int task = t + i * 256;          // 512 tasks: 64 n-rows x 8 k-chunks
    int n = task >> 3, kc = (task & 7) * 8;
    u16 tmp[8];
    #pragma unroll
    for (int j = 0; j < 8; j++)
      tmp[j] = f2b(W[(size_t)(k0 + kc + j) * N + n0 + n]);
    *(uint4*)&Wt[(size_t)(n0 + n) * K + k0 + kc] = *(uint4*)tmp;
  }
}

// ---------------- LayerNorm: one wave per 512-wide fp32 row, 4 rows/block ----------------
template<int OUTF32>
__global__ __launch_bounds__(256) void ln_kernel(const float* __restrict__ x,
    const float* __restrict__ w, const float* __restrict__ b, void* __restrict__ out)
{
  int row  = blockIdx.x * 4 + (threadIdx.x >> 6);
  int lane = threadIdx.x & 63;
  const float* xr = x + (size_t)row * DIMM;
  float4 a = ((const float4*)xr)[lane * 2];
  float4 c = ((const float4*)xr)[lane * 2 + 1];
  float f[8] = { a.x, a.y, a.z, a.w, c.x, c.y, c.z, c.w };

  float s = 0.f, ss = 0.f;
  #pragma unroll
  for (int i = 0; i < 8; i++) { s += f[i]; ss += f[i] * f[i]; }
  #pragma unroll
  for (int off = 32; off > 0; off >>= 1) {
    s  += __shfl_xor(s,  off);
    ss += __shfl_xor(ss, off);
  }
  float mu  = s * (1.f / 512.f);
  float var = ss * (1.f / 512.f) - mu * mu;
  float rs  = rsqrtf(var + 1e-5f);

  float4 w0 = ((const float4*)w)[lane * 2], w1 = ((const float4*)w)[lane * 2 + 1];
  float4 b0 = ((const float4*)b)[lane * 2], b1 = ((const float4*)b)[lane * 2 + 1];
  float wv[8] = { w0.x, w0.y, w0.z, w0.w, w1.x, w1.y, w1.z, w1.w };
  float bv[8] = { b0.x, b0.y, b0.z, b0.w, b1.x, b1.y, b1.z, b1.w };

  if (OUTF32) {
    float res[8];
    #pragma unroll
    for (int i = 0; i < 8; i++) res[i] = (f[i] - mu) * rs * wv[i] + bv[i];
    float* orow = (float*)out + (size_t)row * DIMM;
    ((float4*)orow)[lane * 2]     = *(float4*)&res[0];
    ((float4*)orow)[lane * 2 + 1] = *(float4*)&res[4];
  } else {
    u16 res[8];
    #pragma unroll
    for (int i = 0; i < 8; i++) res[i] = f2b((f[i] - mu) * rs * wv[i] + bv[i]);
    ((uint4*)((u16*)out + (size_t)row * DIMM))[lane] = *(uint4*)res;
  }
}

// ---------------- 256x256 BK=32 3-phase pipelined GEMM: C[M,Nd] = A[M,K] @ Bt[Nd,K]^T + bias ----------------
// 8 waves (2M x 4N), BK=32, 64 KiB LDS -> 2 blocks/CU (cross-block overlap + no round tail),
// counted vmcnt(2), T2 swizzle via pre-swizzled global source, T5 setprio, T1 XCD swizzle.
// EPI: 0 = bias (bf16 out), 1 = bias + fp32 residual (fp32 out), 2 = bias + exact GELU (bf16 out)
template<int EPI>
__global__ __launch_bounds__(512, 4) void gemm256(
    const u16* __restrict__ A, const u16* __restrict__ Bt,
    const float* __restrict__ bias, const float* __restrict__ resid,
    void* __restrict__ Cv, int Nd, int K, int gx)
{
  __shared__ u16 As[2][2][128][32];
  __shared__ u16 Bs[2][2][128][32];

  // T1: bijective XCD-aware remap (m204 variant; works for nwg % 8 != 0)
  int nwg  = gridDim.x;
  int orig = blockIdx.x;
  int xcd = orig & 7, cidx = orig >> 3;
  int qq = nwg >> 3, rr8 = nwg & 7;
  int nid = (xcd < rr8 ? xcd * (qq + 1) : rr8 * (qq + 1) + (xcd - rr8) * qq) + cidx;
  int bx = nid % gx, by = nid / gx;
  int m0 = by * 256, n0 = bx * 256;

  int t = threadIdx.x;
  int w = t >> 6, l = t & 63;
  int wr = w >> 2, wc = w & 3, quad = l >> 4, l16 = l & 15;
  int KT = K >> 5;

  // staging: wave w covers rows {16w..16w+15} of each 128-row half-tile, 1 gld16/lane (16B);
  // source k-chunk pre-swizzled so linear LDS dest realizes slot ^= (row&3)^((row>>2)&3)
  int rloc   = (w << 4) + (l >> 2);                                   // row in half-tile
  int schunk = (((l & 3) ^ ((l >> 2) & 3) ^ ((l >> 4) & 3)) << 3);    // source elem offset
  const u16* gA = A  + (size_t)m0 * K;
  const u16* gB = Bt + (size_t)n0 * K;
  int rsx = (l16 & 3) ^ ((l16 >> 2) & 3);                             // read-side swizzle

  auto STAGE = [&](int ktj, int h) {   // h: 0=A half0, 1=A half1, 2=B half0, 3=B half1
    int c = ktj & 1;
    u16* lb = (h < 2) ? &As[c][h][0][0] : &Bs[c][h - 2][0][0];
    const u16* g = ((h < 2) ? gA : gB)
                 + (size_t)(((h & 1) << 7) + rloc) * K + ktj * 32 + schunk;
    gld16(lb + (w << 9), g);
  };

  // prologue: K-tile 0 fully + A-halves of K-tile 1 (6 half-tiles in flight)
  STAGE(0, 0); STAGE(0, 1); STAGE(0, 2); STAGE(0, 3);
  STAGE(1, 0); STAGE(1, 1);
  asm volatile("s_waitcnt vmcnt(2)" ::: "memory");
  __builtin_amdgcn_s_barrier();
  __builtin_amdgcn_sched_barrier(0);

  floatx4 zero = {0.f, 0.f, 0.f, 0.f};
  floatx4 acc[8][4];
  #pragma unroll
  for (int mt = 0; mt < 8; mt++)
    #pragma unroll
    for (int nt = 0; nt < 4; nt++) acc[mt][nt] = zero;

  for (int kt = 0; kt < KT; ++kt) {
    int c = kt & 1;
    const u16 (*Ah)[32] = As[c][wr];
    const u16 (*Bh)[32] = Bs[c][wc >> 1];
    int bl = (wc & 1) * 64;

    short8 af[8], bf[4];

    // ---- phase 0: read A m0-3 + B n0-1 (6 ds_read); stage kt+1 B-half0; MFMA m0-3 x n0-1
    #pragma unroll
    for (int mt = 0; mt < 4; mt++)
      af[mt] = *(const short8*)&Ah[mt * 16 + l16][(quad ^ rsx) << 3];
    #pragma unroll
    for (int nt = 0; nt < 2; nt++)
      bf[nt] = *(const short8*)&Bh[bl + nt * 16 + l16][(quad ^ rsx) << 3];
    { int j = 4 * kt + 6; if (j < 4 * KT) STAGE(j >> 2, j & 3); }
    __builtin_amdgcn_s_barrier();
    __builtin_amdgcn_s_setprio(1);
    #pragma unroll
    for (int nt = 0; nt < 2; nt++)
      #pragma unroll
      for (int mt = 0; mt < 4; mt++)
        acc[mt][nt] = __builtin_amdgcn_mfma_f32_16x16x32_bf16(af[mt], bf[nt], acc[mt][nt], 0, 0, 0);
    __builtin_amdgcn_s_setprio(0);
    __builtin_amdgcn_s_barrier();

    // ---- phase 1: read A m4-7 + B n2-3; stage kt+1 B-half1; MFMA m4-7 x n2-3
    #pragma unroll
    for (int mt = 4; mt < 8; mt++)
      af[mt] = *(const short8*)&Ah[mt * 16 + l16][(quad ^ rsx) << 3];
    #pragma unroll
    for (int nt = 2; nt < 4; nt++)
      bf[nt] = *(const short8*)&Bh[bl + nt * 16 + l16][(quad ^ rsx) << 3];
    { int j = 4 * kt + 7; if (j < 4 * KT) STAGE(j >> 2, j & 3); }
    __builtin_amdgcn_s_barrier();
    __builtin_amdgcn_s_setprio(1);
    #pragma unroll
    for (int nt = 2; nt < 4; nt++)
      #pragma unroll
      for (int mt = 4; mt < 8; mt++)
        acc[mt][nt] = __builtin_amdgcn_mfma_f32_16x16x32_bf16(af[mt], bf[nt], acc[mt][nt], 0, 0, 0);
    __builtin_amdgcn_s_setprio(0);
    __builtin_amdgcn_s_barrier();

    // ---- phase 2: no reads (all buf[c] ds_reads drained before ph1-end barrier);
    //      stage kt+2 A-halves into buf[c] (safe now); MFMA cross quadrants (frags in regs)
    { int j = 4 * kt + 8; if (j < 4 * KT) STAGE(j >> 2, j & 3); }
    { int j = 4 * kt + 9; if (j < 4 * KT) STAGE(j >> 2, j & 3); }
    __builtin_amdgcn_s_setprio(1);
    #pragma unroll
    for (int nt = 2; nt < 4; nt++)
      #pragma unroll
      for (int mt = 0; mt < 4; mt++)
        acc[mt][nt] = __builtin_amdgcn_mfma_f32_16x16x32_bf16(af[mt], bf[nt], acc[mt][nt], 0, 0, 0);
    #pragma unroll
    for (int nt = 0; nt < 2; nt++)
      #pragma unroll
      for (int mt = 4; mt < 8; mt++)
        acc[mt][nt] = __builtin_amdgcn_mfma_f32_16x16x32_bf16(af[mt], bf[nt], acc[mt][nt], 0, 0, 0);
    __builtin_amdgcn_s_setprio(0);

    if (kt < KT - 1) {
      if (kt == KT - 2) asm volatile("s_waitcnt vmcnt(0)" ::: "memory");
      else              asm volatile("s_waitcnt vmcnt(2)" ::: "memory");
      __builtin_amdgcn_s_barrier();
      __builtin_amdgcn_sched_barrier(0);
    }
  }

  // epilogue: D row = quad*4+r, col = l16
  #pragma unroll
  for (int mt = 0; mt < 8; mt++) {
    #pragma unroll
    for (int nt = 0; nt < 4; nt++) {
      int nc = n0 + wc * 64 + nt * 16 + l16;
      float bv = bias[nc];
      #pragma unroll
      for (int r = 0; r < 4; r++) {
        int mr = m0 + wr * 128 + mt * 16 + quad * 4 + r;
        size_t idx = (size_t)mr * Nd + nc;
        float v = acc[mt][nt][r] + bv;
        if constexpr (EPI == 1) {
          ((float*)Cv)[idx] = v + resid[idx];
        } else if constexpr (EPI == 2) {
          v = 0.5f * v * (1.f + erff(v * 0.70710678118654752f));
          ((u16*)Cv)[idx] = f2b(v);
        } else {
          ((u16*)Cv)[idx] = f2b(v);
        }
      }
    }
  }
}

// ---------------- MFMA attention (RoPE fused): one block per (batch, head) ----------------
__device__ __forceinline__ int grp(int tk) { return tk == 0 ? 0 : (tk < 5 ? 1 : (tk < 21 ? 2 : 3)); }

__global__ __launch_bounds__(256) void attn_kernel(const u16* __restrict__ qkv,
    const float* __restrict__ coords, u16* __restrict__ out)
{
  __shared__ u16 Qs[96 * 72];   // [token][d], stride 72
  __shared__ u16 Ks[96 * 72];   // [token][d]
  __shared__ u16 Vt[64 * 104];  // [d][token], stride 104
  __shared__ u16 Pb[96 * 104];  // [row][col] softmax probs, bf16

  int b = blockIdx.x >> 3, h = blockIdx.x & 7;
  int tid = threadIdx.x;
  const u16* base = qkv + ((size_t)b * 85) * 1536 + h * 64;

  for (int idx = tid; idx < 96 * 64; idx += 256) {
    int tk = idx >> 6, d = idx & 63;
    float qv = 0.f, kv = 0.f; u16 vv = 0;
    if (tk < 85) {
      const u16* qp = base + (size_t)tk * 1536;
      vv = qp[1024 + d];
      if (tk == 0) {
        qv = b2f(qp[d]); kv = b2f(qp[512 + d]);
      } else {
        int j = d & 15, q4 = d >> 4;
        float coord = coords[(tk - 1) * 2 + (q4 >> 1)];
        float freq = __expf((float)j * -0.14391156831212787f);  // -ln(10)/16
        float ang = coord * freq * 6.283185307179586f;
        float sn, cs; __sincosf(ang, &sn, &cs);
        int p0 = ((q4 & 2) << 4) + j, p1 = p0 + 16;
        float a0 = b2f(qp[p0]),       a1 = b2f(qp[p1]);
        float k0 = b2f(qp[512 + p0]), k1 = b2f(qp[512 + p1]);
        if (q4 & 1) { qv = a0 * sn + a1 * cs; kv = k0 * sn + k1 * cs; }
        else        { qv = a0 * cs - a1 * sn; kv = k0 * cs - k1 * sn; }
      }
    }
    Qs[tk * 72 + d] = f2b(qv);
    Ks[tk * 72 + d] = f2b(kv);
    Vt[d * 104 + tk] = vv;
  }
  __syncthreads();

  int wave = tid >> 6, lane = tid & 63, quad = lane >> 4, l16 = lane & 15;
  const unsigned MBITS = 0x8539u;
  floatx4 zero = {0.f, 0.f, 0.f, 0.f};

  int nb = (wave < 2) ? 2 : 1;     // 6 row-bands of 16 over 4 waves: {0,4},{1,5},{2},{3}
  for (int bi = 0; bi < nb; bi++) {
    int band = (bi == 0) ? wave : wave + 4;

    // S = Q K^T (frag = 8 elems at k = quad*8 + 32*kstep)
    short8 a0 = *(const short8*)&Qs[(band * 16 + l16) * 72 + quad * 8];
    short8 a1 = *(const short8*)&Qs[(band * 16 + l16) * 72 + 32 + quad * 8];
    floatx4 s[6];
    #pragma unroll
    for (int nt = 0; nt < 6; nt++) {
      short8 b0 = *(const short8*)&Ks[(nt * 16 + l16) * 72 + quad * 8];
      short8 b1 = *(const short8*)&Ks[(nt * 16 + l16) * 72 + 32 + quad * 8];
      floatx4 tmp = __builtin_amdgcn_mfma_f32_16x16x32_bf16(a0, b0, zero, 0, 0, 0);
      s[nt] = __builtin_amdgcn_mfma_f32_16x16x32_bf16(a1, b1, tmp, 0, 0, 0);
    }

    int rb = band * 16 + quad * 4;
    #pragma unroll
    for (int r = 0; r < 4; r++) {
      int row = rb + r, gr = grp(row);
      float mx = -3.4e38f;
      #pragma unroll
      for (int nt = 0; nt < 6; nt++) {
        int col = nt * 16 + l16;
        float m = (col < 85 && ((MBITS >> (gr * 4 + grp(col))) & 1)) ? 0.f : -1e30f;
        s[nt][r] = s[nt][r] * 0.125f + m;
        mx = fmaxf(mx, s[nt][r]);
      }
      #pragma unroll
      for (int off = 1; off < 16; off <<= 1) mx = fmaxf(mx, __shfl_xor(mx, off));
      float sum = 0.f;
      #pragma unroll
      for (int nt = 0; nt < 6; nt++) { s[nt][r] = __expf(s[nt][r] - mx); sum += s[nt][r]; }
      #pragma unroll
      for (int off = 1; off < 16; off <<= 1) sum += __shfl_xor(sum, off);
      float inv = 1.f / sum;
      #pragma unroll
      for (int nt = 0; nt < 6; nt++)
        Pb[row * 104 + nt * 16 + l16] = f2b(s[nt][r] * inv);
    }

    // O = P V (in-wave LDS RAW on Pb: wave reads only rows it wrote)
    floatx4 o[4];
    #pragma unroll
    for (int nt2 = 0; nt2 < 4; nt2++) o[nt2] = zero;
    #pragma unroll
    for (int ks = 0; ks < 3; ks++) {
      short8 pa = *(const short8*)&Pb[(band * 16 + l16) * 104 + ks * 32 + quad * 8];
      #pragma unroll
      for (int nt2 = 0; nt2 < 4; nt2++) {
        short8 vb = *(const short8*)&Vt[(nt2 * 16 + l16) * 104 + ks * 32 + quad * 8];
        o[nt2] = __builtin_amdgcn_mfma_f32_16x16x32_bf16(pa, vb, o[nt2], 0, 0, 0);
      }
    }
    #pragma unroll
    for (int nt2 = 0; nt2 < 4; nt2++) {
      #pragma unroll
      for (int r = 0; r < 4; r++) {
        int row = rb + r;
        if (row < 85)
          out[((size_t)b * 85 + row) * 512 + h * 64 + nt2 * 16 + l16] = f2b(o[nt2][r]);
      }
    }
  }
}

extern "C" void kernel_launch(void* const* d_in, const int* in_sizes, int n_in,
                              void* d_out, int out_size, void* d_ws, size_t ws_size,
                              hipStream_t stream) {
  (void)in_sizes; (void)n_in; (void)out_size; (void)ws_size;
  const float* x_in   = (const float*)d_in[0];
  const float* coords = (const float*)d_in[1];
  const float* ln1_w  = (const float*)d_in[2];
  const float* ln1_b  = (const float*)d_in[3];
  const float* qkv_w  = (const float*)d_in[4];
  const float* qkv_b  = (const float*)d_in[5];
  const float* proj_w = (const float*)d_in[6];
  const float* proj_b = (const float*)d_in[7];
  const float* ln2_w  = (const float*)d_in[8];
  const float* ln2_b  = (const float*)d_in[9];
  const float* fc1_w  = (const float*)d_in[10];
  const float* fc1_b  = (const float*)d_in[11];
  const float* fc2_w  = (const float*)d_in[12];
  const float* fc2_b  = (const float*)d_in[13];
  const float* lnf_w  = (const float*)d_in[14];
  const float* lnf_b  = (const float*)d_in[15];

  float* xb = (float*)d_ws;                       // fp32 residual stream
  u16*   hb = (u16*)(xb + (size_t)MTOT * 512);    // bf16 ln/attn buffer
  u16*   qb = hb + (size_t)MTOT * 512;            // bf16 qkv / fc1 buffer
  u16*   wbuf = qb + (size_t)MTOT * 2048;         // transposed bf16 weights
  u16* wq = wbuf;
  u16* wp = wq + (size_t)6 * 512 * 1536;
  u16* w1 = wp + (size_t)6 * 512 * 512;
  u16* w2 = w1 + (size_t)6 * 512 * 2048;

  dim3 blk(256);
  dim3 blkg(512);
  transpose_conv<<<dim3(1536 / 64, 512 / 64, 6), blk, 0, stream>>>(qkv_w, wq, 512, 1536);
  transpose_conv<<<dim3(512 / 64, 512 / 64, 6), blk, 0, stream>>>(proj_w, wp, 512, 512);
  transpose_conv<<<dim3(2048 / 64, 512 / 64, 6), blk, 0, stream>>>(fc1_w, w1, 512, 2048);
  transpose_conv<<<dim3(512 / 64, 2048 / 64, 6), blk, 0, stream>>>(fc2_w, w2, 2048, 512);

  const int MT = MTOT / 256;  // 170 m-tiles
  for (int l = 0; l < 6; l++) {
    const float* xcur = (l == 0) ? x_in : xb;
    ln_kernel<0><<<MTOT / 4, blk, 0, stream>>>(xcur, ln1_w + l * 512, ln1_b + l * 512, hb);
    gemm256<0><<<6 * MT, blkg, 0, stream>>>(
        hb, wq + (size_t)l * 512 * 1536, qkv_b + (size_t)l * 1536, nullptr, qb, 1536, 512, 6);
    attn_kernel<<<512 * NHEAD, blk, 0, stream>>>(qb, coords, hb);
    gemm256<1><<<2 * MT, blkg, 0, stream>>>(
        hb, wp + (size_t)l * 512 * 512, proj_b + (size_t)l * 512, xcur, xb, 512, 512, 2);
    ln_kernel<0><<<MTOT / 4, blk, 0, stream>>>(xb, ln2_w + l * 512, ln2_b + l * 512, hb);
    gemm256<2><<<8 * MT, blkg, 0, stream>>>(
        hb, w1 + (size_t)l * 512 * 2048, fc1_b + (size_t)l * 2048, nullptr, qb, 2048, 512, 8);
    gemm256<1><<<2 * MT, blkg, 0, stream>>>(
        qb, w2 + (size_t)l * 2048 * 512, fc2_b + (size_t)l * 512, xb, xb, 512, 2048, 2);
  }
  ln_kernel<1><<<MTOT / 4, blk, 0, stream>>>(xb, lnf_w, lnf_b, d_out);
}

// Round 3
// 4028.025 us; speedup vs baseline: 5.3030x; 5.3030x over previous
//
#include <hip/hip_runtime.h>
#include <hip/hip_bf16.h>

typedef unsigned short u16;
typedef unsigned int u32;
typedef __attribute__((ext_vector_type(8))) short short8;
typedef __attribute__((ext_vector_type(4))) float floatx4;

#define MTOT 43520   // B*N = 512*85
#define DIMM 512
#define NHEAD 8

__device__ __forceinline__ float b2f(u16 u) { return __uint_as_float(((unsigned)u) << 16); }
__device__ __forceinline__ u16 f2b(float f) {
  unsigned u = __float_as_uint(f);
  return (u16)((u + 0x7FFFu + ((u >> 16) & 1u)) >> 16);  // RNE; inputs always finite
}

// async global->LDS, 16B per lane; lds base must be wave-uniform, data lands at base + lane*16
__device__ __forceinline__ void gld16(void* lds, const void* g) {
  __builtin_amdgcn_global_load_lds(
      (const __attribute__((address_space(1))) u32*)g,
      (__attribute__((address_space(3))) u32*)lds, 16, 0, 0);
}

// ---------------- transpose + fp32->bf16: W[K][N] f32 -> Wt[N][K] bf16, per layer z ----------------
__global__ __launch_bounds__(256) void transpose_conv(const float* __restrict__ in,
    u16* __restrict__ out, int K, int N)
{
  const float* W  = in  + (size_t)blockIdx.z * K * N;
  u16*         Wt = out + (size_t)blockIdx.z * K * N;
  int n0 = blockIdx.x * 64, k0 = blockIdx.y * 64;
  int t = threadIdx.x;
  #pragma unroll
  for (int i = 0; i < 2; i++) {
    int task = t + i * 256;          // 512 tasks: 64 n-rows x 8 k-chunks
    int n = task >> 3, kc = (task & 7) * 8;
    u16 tmp[8];
    #pragma unroll
    for (int j = 0; j < 8; j++)
      tmp[j] = f2b(W[(size_t)(k0 + kc + j) * N + n0 + n]);
    *(uint4*)&Wt[(size_t)(n0 + n) * K + k0 + kc] = *(uint4*)tmp;
  }
}

// ---------------- LayerNorm: one wave per 512-wide fp32 row, 4 rows/block ----------------
template<int OUTF32>
__global__ __launch_bounds__(256) void ln_kernel(const float* __restrict__ x,
    const float* __restrict__ w, const float* __restrict__ b, void* __restrict__ out)
{
  int row  = blockIdx.x * 4 + (threadIdx.x >> 6);
  int lane = threadIdx.x & 63;
  const float* xr = x + (size_t)row * DIMM;
  float4 a = ((const float4*)xr)[lane * 2];
  float4 c = ((const float4*)xr)[lane * 2 + 1];
  float f[8] = { a.x, a.y, a.z, a.w, c.x, c.y, c.z, c.w };

  float s = 0.f, ss = 0.f;
  #pragma unroll
  for (int i = 0; i < 8; i++) { s += f[i]; ss += f[i] * f[i]; }
  #pragma unroll
  for (int off = 32; off > 0; off >>= 1) {
    s  += __shfl_xor(s,  off);
    ss += __shfl_xor(ss, off);
  }
  float mu  = s * (1.f / 512.f);
  float var = ss * (1.f / 512.f) - mu * mu;
  float rs  = rsqrtf(var + 1e-5f);

  float4 w0 = ((const float4*)w)[lane * 2], w1 = ((const float4*)w)[lane * 2 + 1];
  float4 b0 = ((const float4*)b)[lane * 2], b1 = ((const float4*)b)[lane * 2 + 1];
  float wv[8] = { w0.x, w0.y, w0.z, w0.w, w1.x, w1.y, w1.z, w1.w };
  float bv[8] = { b0.x, b0.y, b0.z, b0.w, b1.x, b1.y, b1.z, b1.w };

  if (OUTF32) {
    float res[8];
    #pragma unroll
    for (int i = 0; i < 8; i++) res[i] = (f[i] - mu) * rs * wv[i] + bv[i];
    float* orow = (float*)out + (size_t)row * DIMM;
    ((float4*)orow)[lane * 2]     = *(float4*)&res[0];
    ((float4*)orow)[lane * 2 + 1] = *(float4*)&res[4];
  } else {
    u16 res[8];
    #pragma unroll
    for (int i = 0; i < 8; i++) res[i] = f2b((f[i] - mu) * rs * wv[i] + bv[i]);
    ((uint4*)((u16*)out + (size_t)row * DIMM))[lane] = *(uint4*)res;
  }
}

// ---------------- 256x256 BK=64 persistent pipelined GEMM: C[M,Nd] = A[M,K] @ Bt[Nd,K]^T + bias ----------------
// 8 waves (2M x 4N), BK=64, 128 KiB LDS, 1 block/CU persistent over tiles; the half-tile staging
// stream CONTINUES across tile boundaries (KT even -> buffer parity continues), so the pipeline
// never drains except at each block's last tile. Counted vmcnt(4); T2 swizzle via pre-swizzled
// global source (8 16B slots -> conflict-free b128); T5 setprio; XCD-contiguous tile assignment.
// EPI: 0 = bias (bf16 out), 1 = bias + fp32 residual (fp32 out), 2 = bias + exact GELU (bf16 out)
template<int EPI>
__global__ __launch_bounds__(512, 2) void gemm256(
    const u16* __restrict__ A, const u16* __restrict__ Bt,
    const float* __restrict__ bias, const float* __restrict__ resid,
    void* __restrict__ Cv, int Nd, int K, int gx, int ntiles)
{
  __shared__ u16 As[2][2][128][64];
  __shared__ u16 Bs[2][2][128][64];

  // XCD-contiguous block id: XCD x gets nid [x*nwg/8, (x+1)*nwg/8)
  int nwg  = gridDim.x;
  int orig = blockIdx.x;
  int xcd = orig & 7, cidx = orig >> 3;
  int qq = nwg >> 3, rr8 = nwg & 7;
  int nid = (xcd < rr8 ? xcd * (qq + 1) : rr8 * (qq + 1) + (xcd - rr8) * qq) + cidx;
  if (nid >= ntiles) return;

  int t = threadIdx.x;
  int w = t >> 6, l = t & 63;
  int wr = w >> 2, wc = w & 3, quad = l >> 4, l16 = l & 15;
  int KT = K >> 6;

  // staging: wave w stages rows {8w..8w+7} and {64+8w..} of each 128-row half-tile;
  // source k-slot pre-swizzled so linear gld16 dest realizes slot ^= (row&7)
  int Rb = 8 * w + (l >> 3);
  int slog8 = (((l & 7) ^ ((l >> 3) & 7)) << 3);
  int sx = l16 & 7;  // read-side swizzle xor

  // current tile
  int tcur = nid;
  int by = tcur / gx, bx = tcur - by * gx;
  int m0 = by * 256, n0 = bx * 256;
  const u16* gAc = A  + (size_t)m0 * K + slog8;
  const u16* gBc = Bt + (size_t)n0 * K + slog8;
  // next tile (stride = grid size)
  int tn = tcur + nwg;
  bool havenext = tn < ntiles;
  int m0n = m0, n0n = n0;
  const u16* gAn = gAc;
  const u16* gBn = gBc;
  if (havenext) {
    int byn = tn / gx, bxn = tn - byn * gx;
    m0n = byn * 256; n0n = bxn * 256;
    gAn = A  + (size_t)m0n * K + slog8;
    gBn = Bt + (size_t)n0n * K + slog8;
  }

  // STAGE(j): j = 4*ktj + h, ktj may run into the NEXT tile (ktj >= KT).
  // h: 0=A half0, 1=A half1, 2=B half0, 3=B half1. Each STAGE = 2 gld16 per lane.
  auto STAGE = [&](int j) {
    int ktj = j >> 2, h = j & 3;
    bool nxt = ktj >= KT;
    if (nxt && !havenext) return;
    int kk = nxt ? ktj - KT : ktj;
    const u16* gbase = (h < 2) ? (nxt ? gAn : gAc) : (nxt ? gBn : gBc);
    int c = ktj & 1;                      // parity continues across boundary (KT even)
    u16* lb = (h < 2) ? &As[c][h & 1][0][0] : &Bs[c][h & 1][0][0];
    const u16* g = gbase + (size_t)((h & 1) * 128 + Rb) * K + kk * 64;
    gld16(lb + w * 512,       g);
    gld16(lb + (8 + w) * 512, g + (size_t)64 * K);
  };

  // prologue: first tile's K-tile 0 fully + A-halves of K-tile 1
  STAGE(0); STAGE(1); STAGE(2); STAGE(3); STAGE(4); STAGE(5);
  asm volatile("s_waitcnt vmcnt(4)" ::: "memory");
  __builtin_amdgcn_s_barrier();
  __builtin_amdgcn_sched_barrier(0);

  floatx4 zero = {0.f, 0.f, 0.f, 0.f};
  floatx4 acc[8][4];

  while (true) {
    #pragma unroll
    for (int mt = 0; mt < 8; mt++)
      #pragma unroll
      for (int nt = 0; nt < 4; nt++) acc[mt][nt] = zero;

    for (int kt = 0; kt < KT; ++kt) {
      int c = kt & 1;
      const u16 (*Ah)[64] = As[c][wr];
      const u16 (*Bh)[64] = Bs[c][wc >> 1];
      int bl = (wc & 1) * 64;

      short8 af[8][2], bf[4][2];

      // ---- phase 0: read A m0-3 + B n0-1; stage (kt+1,B0); MFMA m0-3 x n0-1
      #pragma unroll
      for (int mt = 0; mt < 4; mt++)
        #pragma unroll
        for (int kk = 0; kk < 2; kk++)
          af[mt][kk] = *(const short8*)&Ah[mt * 16 + l16][((kk * 4 + quad) ^ sx) << 3];
      #pragma unroll
      for (int nt = 0; nt < 2; nt++)
        #pragma unroll
        for (int kk = 0; kk < 2; kk++)
          bf[nt][kk] = *(const short8*)&Bh[bl + nt * 16 + l16][((kk * 4 + quad) ^ sx) << 3];
      STAGE(4 * kt + 6);
      __builtin_amdgcn_s_barrier();
      __builtin_amdgcn_s_setprio(1);
      #pragma unroll
      for (int nt = 0; nt < 2; nt++)
        #pragma unroll
        for (int mt = 0; mt < 4; mt++)
          #pragma unroll
          for (int kk = 0; kk < 2; kk++)
            acc[mt][nt] = __builtin_amdgcn_mfma_f32_16x16x32_bf16(af[mt][kk], bf[nt][kk], acc[mt][nt], 0, 0, 0);
      __builtin_amdgcn_s_setprio(0);
      __builtin_amdgcn_s_barrier();

      // ---- phase 1: read A m4-7 + B n2-3; stage (kt+1,B1); MFMA m4-7 x n2-3
      #pragma unroll
      for (int mt = 4; mt < 8; mt++)
        #pragma unroll
        for (int kk = 0; kk < 2; kk++)
          af[mt][kk] = *(const short8*)&Ah[mt * 16 + l16][((kk * 4 + quad) ^ sx) << 3];
      #pragma unroll
      for (int nt = 2; nt < 4; nt++)
        #pragma unroll
        for (int kk = 0; kk < 2; kk++)
          bf[nt][kk] = *(const short8*)&Bh[bl + nt * 16 + l16][((kk * 4 + quad) ^ sx) << 3];
      STAGE(4 * kt + 7);
      __builtin_amdgcn_s_barrier();
      __builtin_amdgcn_s_setprio(1);
      #pragma unroll
      for (int nt = 2; nt < 4; nt++)
        #pragma unroll
        for (int mt = 4; mt < 8; mt++)
          #pragma unroll
          for (int kk = 0; kk < 2; kk++)
            acc[mt][nt] = __builtin_amdgcn_mfma_f32_16x16x32_bf16(af[mt][kk], bf[nt][kk], acc[mt][nt], 0, 0, 0);
      __builtin_amdgcn_s_setprio(0);
      __builtin_amdgcn_s_barrier();

      // ---- phase 2: no reads (all buf[c] ds_reads done by ph1-end barrier);
      //      stage (kt+2,A0) into buf[c] (safe now); MFMA m0-3 x n2-3
      STAGE(4 * kt + 8);
      __builtin_amdgcn_s_barrier();
      __builtin_amdgcn_s_setprio(1);
      #pragma unroll
      for (int nt = 2; nt < 4; nt++)
        #pragma unroll
        for (int mt = 0; mt < 4; mt++)
          #pragma unroll
          for (int kk = 0; kk < 2; kk++)
            acc[mt][nt] = __builtin_amdgcn_mfma_f32_16x16x32_bf16(af[mt][kk], bf[nt][kk], acc[mt][nt], 0, 0, 0);
      __builtin_amdgcn_s_setprio(0);
      __builtin_amdgcn_s_barrier();

      // ---- phase 3: stage (kt+2,A1); MFMA m4-7 x n0-1; counted vmcnt at tile end
      STAGE(4 * kt + 9);
      __builtin_amdgcn_s_barrier();
      __builtin_amdgcn_s_setprio(1);
      #pragma unroll
      for (int nt = 0; nt < 2; nt++)
        #pragma unroll
        for (int mt = 4; mt < 8; mt++)
          #pragma unroll
          for (int kk = 0; kk < 2; kk++)
            acc[mt][nt] = __builtin_amdgcn_mfma_f32_16x16x32_bf16(af[mt][kk], bf[nt][kk], acc[mt][nt], 0, 0, 0);
      __builtin_amdgcn_s_setprio(0);

      if (kt < KT - 1) {
        // last tile of this block: stages into "next" were skipped, so the count-based
        // wait must fully drain at KT-2 to guarantee (KT-1,B*) arrival
        if (kt == KT - 2 && !havenext) asm volatile("s_waitcnt vmcnt(0)" ::: "memory");
        else                           asm volatile("s_waitcnt vmcnt(4)" ::: "memory");
        __builtin_amdgcn_s_barrier();
        __builtin_amdgcn_sched_barrier(0);
      }
    }

    // boundary: guarantee next tile's ktj=0 data is in LDS, BEFORE the epilogue issues
    // its stores (so stores fly during the wait-free start of the next tile)
    if (havenext) asm volatile("s_waitcnt vmcnt(4)" ::: "memory");

    // epilogue: D row = quad*4+r, col = l16
    #pragma unroll
    for (int mt = 0; mt < 8; mt++) {
      #pragma unroll
      for (int nt = 0; nt < 4; nt++) {
        int nc = n0 + wc * 64 + nt * 16 + l16;
        float bv = bias[nc];
        #pragma unroll
        for (int r = 0; r < 4; r++) {
          int mr = m0 + wr * 128 + mt * 16 + quad * 4 + r;
          size_t idx = (size_t)mr * Nd + nc;
          float v = acc[mt][nt][r] + bv;
          if constexpr (EPI == 1) {
            ((float*)Cv)[idx] = v + resid[idx];
          } else if constexpr (EPI == 2) {
            v = 0.5f * v * (1.f + erff(v * 0.70710678118654752f));
            ((u16*)Cv)[idx] = f2b(v);
          } else {
            ((u16*)Cv)[idx] = f2b(v);
          }
        }
      }
    }

    if (!havenext) break;

    // rotate to next tile
    m0 = m0n; n0 = n0n; gAc = gAn; gBc = gBn;
    tn += nwg;
    havenext = tn < ntiles;
    if (havenext) {
      int byn = tn / gx, bxn = tn - byn * gx;
      m0n = byn * 256; n0n = bxn * 256;
      gAn = A  + (size_t)m0n * K + slog8;
      gBn = Bt + (size_t)n0n * K + slog8;
    }
    __builtin_amdgcn_s_barrier();
    __builtin_amdgcn_sched_barrier(0);
  }
}

// ---------------- MFMA attention (RoPE fused): one block per (batch, head) ----------------
__device__ __forceinline__ int grp(int tk) { return tk == 0 ? 0 : (tk < 5 ? 1 : (tk < 21 ? 2 : 3)); }

__global__ __launch_bounds__(256) void attn_kernel(const u16* __restrict__ qkv,
    const float* __restrict__ coords, u16* __restrict__ out)
{
  __shared__ u16 Qs[96 * 72];   // [token][d], stride 72
  __shared__ u16 Ks[96 * 72];   // [token][d]
  __shared__ u16 Vt[64 * 104];  // [d][token], stride 104
  __shared__ u16 Pb[96 * 104];  // [row][col] softmax probs, bf16

  int b = blockIdx.x >> 3, h = blockIdx.x & 7;
  int tid = threadIdx.x;
  const u16* base = qkv + ((size_t)b * 85) * 1536 + h * 64;

  for (int idx = tid; idx < 96 * 64; idx += 256) {
    int tk = idx >> 6, d = idx & 63;
    float qv = 0.f, kv = 0.f; u16 vv = 0;
    if (tk < 85) {
      const u16* qp = base + (size_t)tk * 1536;
      vv = qp[1024 + d];
      if (tk == 0) {
        qv = b2f(qp[d]); kv = b2f(qp[512 + d]);
      } else {
        int j = d & 15, q4 = d >> 4;
        float coord = coords[(tk - 1) * 2 + (q4 >> 1)];
        float freq = __expf((float)j * -0.14391156831212787f);  // -ln(10)/16
        float ang = coord * freq * 6.283185307179586f;
        float sn, cs; __sincosf(ang, &sn, &cs);
        int p0 = ((q4 & 2) << 4) + j, p1 = p0 + 16;
        float a0 = b2f(qp[p0]),       a1 = b2f(qp[p1]);
        float k0 = b2f(qp[512 + p0]), k1 = b2f(qp[512 + p1]);
        if (q4 & 1) { qv = a0 * sn + a1 * cs; kv = k0 * sn + k1 * cs; }
        else        { qv = a0 * cs - a1 * sn; kv = k0 * cs - k1 * sn; }
      }
    }
    Qs[tk * 72 + d] = f2b(qv);
    Ks[tk * 72 + d] = f2b(kv);
    Vt[d * 104 + tk] = vv;
  }
  __syncthreads();

  int wave = tid >> 6, lane = tid & 63, quad = lane >> 4, l16 = lane & 15;
  const unsigned MBITS = 0x8539u;
  floatx4 zero = {0.f, 0.f, 0.f, 0.f};

  int nb = (wave < 2) ? 2 : 1;     // 6 row-bands of 16 over 4 waves: {0,4},{1,5},{2},{3}
  for (int bi = 0; bi < nb; bi++) {
    int band = (bi == 0) ? wave : wave + 4;

    // S = Q K^T (frag = 8 elems at k = quad*8 + 32*kstep)
    short8 a0 = *(const short8*)&Qs[(band * 16 + l16) * 72 + quad * 8];
    short8 a1 = *(const short8*)&Qs[(band * 16 + l16) * 72 + 32 + quad * 8];
    floatx4 s[6];
    #pragma unroll
    for (int nt = 0; nt < 6; nt++) {
      short8 b0 = *(const short8*)&Ks[(nt * 16 + l16) * 72 + quad * 8];
      short8 b1 = *(const short8*)&Ks[(nt * 16 + l16) * 72 + 32 + quad * 8];
      floatx4 tmp = __builtin_amdgcn_mfma_f32_16x16x32_bf16(a0, b0, zero, 0, 0, 0);
      s[nt] = __builtin_amdgcn_mfma_f32_16x16x32_bf16(a1, b1, tmp, 0, 0, 0);
    }

    int rb = band * 16 + quad * 4;
    #pragma unroll
    for (int r = 0; r < 4; r++) {
      int row = rb + r, gr = grp(row);
      float mx = -3.4e38f;
      #pragma unroll
      for (int nt = 0; nt < 6; nt++) {
        int col = nt * 16 + l16;
        float m = (col < 85 && ((MBITS >> (gr * 4 + grp(col))) & 1)) ? 0.f : -1e30f;
        s[nt][r] = s[nt][r] * 0.125f + m;
        mx = fmaxf(mx, s[nt][r]);
      }
      #pragma unroll
      for (int off = 1; off < 16; off <<= 1) mx = fmaxf(mx, __shfl_xor(mx, off));
      float sum = 0.f;
      #pragma unroll
      for (int nt = 0; nt < 6; nt++) { s[nt][r] = __expf(s[nt][r] - mx); sum += s[nt][r]; }
      #pragma unroll
      for (int off = 1; off < 16; off <<= 1) sum += __shfl_xor(sum, off);
      float inv = 1.f / sum;
      #pragma unroll
      for (int nt = 0; nt < 6; nt++)
        Pb[row * 104 + nt * 16 + l16] = f2b(s[nt][r] * inv);
    }

    // O = P V (in-wave LDS RAW on Pb: wave reads only rows it wrote)
    floatx4 o[4];
    #pragma unroll
    for (int nt2 = 0; nt2 < 4; nt2++) o[nt2] = zero;
    #pragma unroll
    for (int ks = 0; ks < 3; ks++) {
      short8 pa = *(const short8*)&Pb[(band * 16 + l16) * 104 + ks * 32 + quad * 8];
      #pragma unroll
      for (int nt2 = 0; nt2 < 4; nt2++) {
        short8 vb = *(const short8*)&Vt[(nt2 * 16 + l16) * 104 + ks * 32 + quad * 8];
        o[nt2] = __builtin_amdgcn_mfma_f32_16x16x32_bf16(pa, vb, o[nt2], 0, 0, 0);
      }
    }
    #pragma unroll
    for (int nt2 = 0; nt2 < 4; nt2++) {
      #pragma unroll
      for (int r = 0; r < 4; r++) {
        int row = rb + r;
        if (row < 85)
          out[((size_t)b * 85 + row) * 512 + h * 64 + nt2 * 16 + l16] = f2b(o[nt2][r]);
      }
    }
  }
}

extern "C" void kernel_launch(void* const* d_in, const int* in_sizes, int n_in,
                              void* d_out, int out_size, void* d_ws, size_t ws_size,
                              hipStream_t stream) {
  (void)in_sizes; (void)n_in; (void)out_size; (void)ws_size;
  const float* x_in   = (const float*)d_in[0];
  const float* coords = (const float*)d_in[1];
  const float* ln1_w  = (const float*)d_in[2];
  const float* ln1_b  = (const float*)d_in[3];
  const float* qkv_w  = (const float*)d_in[4];
  const float* qkv_b  = (const float*)d_in[5];
  const float* proj_w = (const float*)d_in[6];
  const float* proj_b = (const float*)d_in[7];
  const float* ln2_w  = (const float*)d_in[8];
  const float* ln2_b  = (const float*)d_in[9];
  const float* fc1_w  = (const float*)d_in[10];
  const float* fc1_b  = (const float*)d_in[11];
  const float* fc2_w  = (const float*)d_in[12];
  const float* fc2_b  = (const float*)d_in[13];
  const float* lnf_w  = (const float*)d_in[14];
  const float* lnf_b  = (const float*)d_in[15];

  float* xb = (float*)d_ws;                       // fp32 residual stream
  u16*   hb = (u16*)(xb + (size_t)MTOT * 512);    // bf16 ln/attn buffer
  u16*   qb = hb + (size_t)MTOT * 512;            // bf16 qkv / fc1 buffer
  u16*   wbuf = qb + (size_t)MTOT * 2048;         // transposed bf16 weights
  u16* wq = wbuf;
  u16* wp = wq + (size_t)6 * 512 * 1536;
  u16* w1 = wp + (size_t)6 * 512 * 512;
  u16* w2 = w1 + (size_t)6 * 512 * 2048;

  dim3 blk(256);
  dim3 blkg(512);
  transpose_conv<<<dim3(1536 / 64, 512 / 64, 6), blk, 0, stream>>>(qkv_w, wq, 512, 1536);
  transpose_conv<<<dim3(512 / 64, 512 / 64, 6), blk, 0, stream>>>(proj_w, wp, 512, 512);
  transpose_conv<<<dim3(2048 / 64, 512 / 64, 6), blk, 0, stream>>>(fc1_w, w1, 512, 2048);
  transpose_conv<<<dim3(512 / 64, 2048 / 64, 6), blk, 0, stream>>>(fc2_w, w2, 2048, 512);

  const int MT = MTOT / 256;  // 170 m-tiles
  const int PG = 256;         // persistent grid: 1 block per CU
  for (int l = 0; l < 6; l++) {
    const float* xcur = (l == 0) ? x_in : xb;
    ln_kernel<0><<<MTOT / 4, blk, 0, stream>>>(xcur, ln1_w + l * 512, ln1_b + l * 512, hb);
    gemm256<0><<<PG, blkg, 0, stream>>>(
        hb, wq + (size_t)l * 512 * 1536, qkv_b + (size_t)l * 1536, nullptr, qb, 1536, 512, 6, 6 * MT);
    attn_kernel<<<512 * NHEAD, blk, 0, stream>>>(qb, coords, hb);
    gemm256<1><<<PG, blkg, 0, stream>>>(
        hb, wp + (size_t)l * 512 * 512, proj_b + (size_t)l * 512, xcur, xb, 512, 512, 2, 2 * MT);
    ln_kernel<0><<<MTOT / 4, blk, 0, stream>>>(xb, ln2_w + l * 512, ln2_b + l * 512, hb);
    gemm256<2><<<PG, blkg, 0, stream>>>(
        hb, w1 + (size_t)l * 512 * 2048, fc1_b + (size_t)l * 2048, nullptr, qb, 2048, 512, 8, 8 * MT);
    gemm256<1><<<PG, blkg, 0, stream>>>(
        qb, w2 + (size_t)l * 2048 * 512, fc2_b + (size_t)l * 512, xb, xb, 512, 2048, 2, 2 * MT);
  }
  ln_kernel<1><<<MTOT / 4, blk, 0, stream>>>(xb, lnf_w, lnf_b, d_out);
}

// Round 6
// 3818.396 us; speedup vs baseline: 5.5942x; 1.0549x over previous
//
#include <hip/hip_runtime.h>
#include <hip/hip_bf16.h>

typedef unsigned short u16;
typedef unsigned int u32;
typedef __attribute__((ext_vector_type(8))) short short8;
typedef __attribute__((ext_vector_type(4))) float floatx4;

#define MTOT 43520   // B*N = 512*85
#define DIMM 512
#define NHEAD 8

__device__ __forceinline__ float b2f(u16 u) { return __uint_as_float(((unsigned)u) << 16); }
__device__ __forceinline__ u16 f2b(float f) {
  unsigned u = __float_as_uint(f);
  return (u16)((u + 0x7FFFu + ((u >> 16) & 1u)) >> 16);  // RNE; inputs always finite
}

// async global->LDS, 16B per lane; lds base must be wave-uniform, data lands at base + lane*16
__device__ __forceinline__ void gld16(void* lds, const void* g) {
  __builtin_amdgcn_global_load_lds(
      (const __attribute__((address_space(1))) u32*)g,
      (__attribute__((address_space(3))) u32*)lds, 16, 0, 0);
}

// ---------------- transpose + fp32->bf16: W[K][N] f32 -> Wt[N][K] bf16, per layer z ----------------
__global__ __launch_bounds__(256) void transpose_conv(const float* __restrict__ in,
    u16* __restrict__ out, int K, int N)
{
  const float* W  = in  + (size_t)blockIdx.z * K * N;
  u16*         Wt = out + (size_t)blockIdx.z * K * N;
  int n0 = blockIdx.x * 64, k0 = blockIdx.y * 64;
  int t = threadIdx.x;
  #pragma unroll
  for (int i = 0; i < 2; i++) {
    int task = t + i * 256;          // 512 tasks: 64 n-rows x 8 k-chunks
    int n = task >> 3, kc = (task & 7) * 8;
    u16 tmp[8];
    #pragma unroll
    for (int j = 0; j < 8; j++)
      tmp[j] = f2b(W[(size_t)(k0 + kc + j) * N + n0 + n]);
    *(uint4*)&Wt[(size_t)(n0 + n) * K + k0 + kc] = *(uint4*)tmp;
  }
}

// ---------------- LayerNorm: one wave per 512-wide fp32 row, 4 rows/block ----------------
template<int OUTF32>
__global__ __launch_bounds__(256) void ln_kernel(const float* __restrict__ x,
    const float* __restrict__ w, const float* __restrict__ b, void* __restrict__ out)
{
  int row  = blockIdx.x * 4 + (threadIdx.x >> 6);
  int lane = threadIdx.x & 63;
  const float* xr = x + (size_t)row * DIMM;
  float4 a = ((const float4*)xr)[lane * 2];
  float4 c = ((const float4*)xr)[lane * 2 + 1];
  float f[8] = { a.x, a.y, a.z, a.w, c.x, c.y, c.z, c.w };

  float s = 0.f, ss = 0.f;
  #pragma unroll
  for (int i = 0; i < 8; i++) { s += f[i]; ss += f[i] * f[i]; }
  #pragma unroll
  for (int off = 32; off > 0; off >>= 1) {
    s  += __shfl_xor(s,  off);
    ss += __shfl_xor(ss, off);
  }
  float mu  = s * (1.f / 512.f);
  float var = ss * (1.f / 512.f) - mu * mu;
  float rs  = rsqrtf(var + 1e-5f);

  float4 w0 = ((const float4*)w)[lane * 2], w1 = ((const float4*)w)[lane * 2 + 1];
  float4 b0 = ((const float4*)b)[lane * 2], b1 = ((const float4*)b)[lane * 2 + 1];
  float wv[8] = { w0.x, w0.y, w0.z, w0.w, w1.x, w1.y, w1.z, w1.w };
  float bv[8] = { b0.x, b0.y, b0.z, b0.w, b1.x, b1.y, b1.z, b1.w };

  if (OUTF32) {
    float res[8];
    #pragma unroll
    for (int i = 0; i < 8; i++) res[i] = (f[i] - mu) * rs * wv[i] + bv[i];
    float* orow = (float*)out + (size_t)row * DIMM;
    ((float4*)orow)[lane * 2]     = *(float4*)&res[0];
    ((float4*)orow)[lane * 2 + 1] = *(float4*)&res[4];
  } else {
    u16 res[8];
    #pragma unroll
    for (int i = 0; i < 8; i++) res[i] = f2b((f[i] - mu) * rs * wv[i] + bv[i]);
    ((uint4*)((u16*)out + (size_t)row * DIMM))[lane] = *(uint4*)res;
  }
}

// ---------------- 128x128 BK=64 pipelined GEMM, one tile per block, 2 blocks/CU ----------------
// 4 waves (2M x 2N), BK=64, 64 KiB LDS + <=256 VGPR -> TWO independent blocks per CU
// (separate barrier groups: one block's MFMA covers the other's barrier/vmcnt stalls).
// NON-persistent: one output tile per block, clean per-tile pipeline, full drain at
// kt=KT-2, epilogue with empty vmem queue. Counted vmcnt mid-loop (units: gld16 instrs;
// invariant 4 outstanding at loop top). T2 swizzle via pre-swizzled global source
// (8 16B slots -> conflict-free ds_read_b128). T5 setprio. Bijective XCD remap.
// EPI: 0 = bias (bf16 out), 1 = bias + fp32 residual (fp32 out), 2 = bias + exact GELU (bf16 out)
template<int EPI>
__global__ __launch_bounds__(256, 2) void gemm128(
    const u16* __restrict__ A, const u16* __restrict__ Bt,
    const float* __restrict__ bias, const float* __restrict__ resid,
    void* __restrict__ Cv, int Nd, int K, int gx)
{
  __shared__ u16 As[2][128][64];
  __shared__ u16 Bs[2][128][64];

  // bijective XCD-contiguous remap (works for any nwg)
  int nwg  = gridDim.x;
  int orig = blockIdx.x;
  int xcd = orig & 7, cidx = orig >> 3;
  int qq = nwg >> 3, rr8 = nwg & 7;
  int nid = (xcd < rr8 ? xcd * (qq + 1) : rr8 * (qq + 1) + (xcd - rr8) * qq) + cidx;
  int by = nid / gx, bx = nid - by * gx;
  int m0 = by * 128, n0 = bx * 128;

  int t = threadIdx.x;
  int w = t >> 6, l = t & 63;
  int wr = w >> 1, wc = w & 1, quad = l >> 4, l16 = l & 15;
  int KT = K >> 6;

  // staging: one STAGE = one 64-row half (64 rows x 64 k = 8 KB) = 2 gld16/lane, wave w
  // covers rows 16w..16w+15. Source k-slot pre-swizzled so the linear LDS dest realizes
  // slot ^= (row&7).
  int Rb = 16 * w + (l >> 3);
  int slog8 = (((l & 7) ^ ((l >> 3) & 7)) << 3);
  int sx = l16 & 7;  // read-side swizzle xor
  const u16* gA = A  + (size_t)m0 * K + slog8;
  const u16* gB = Bt + (size_t)n0 * K + slog8;

  // STAGE(ktj, h): h: 0=A half0 (rows 0-63), 1=A half1, 2=B half0, 3=B half1
  auto STAGE = [&](int ktj, int h) {
    if (ktj >= KT) return;
    int c = ktj & 1;
    u16* lb = (h < 2) ? &As[c][0][0] : &Bs[c][0][0];
    const u16* gbase = (h < 2) ? gA : gB;
    int half = (h & 1) << 6;
    const u16* g = gbase + (size_t)(half + Rb) * K + ktj * 64;
    gld16(lb + (half + 16 * w) * 64,     g);
    gld16(lb + (half + 16 * w + 8) * 64, g + (size_t)8 * K);
  };

  // prologue: K-tile 0 (A0,A1,B0,B1) + K-tile 1 A-halves -> 12 gld16 outstanding
  STAGE(0, 0); STAGE(0, 1); STAGE(0, 2); STAGE(0, 3);
  STAGE(1, 0); STAGE(1, 1);
  asm volatile("s_waitcnt vmcnt(4)" ::: "memory");   // drain 8 = K-tile 0; A(kt1) in flight
  __builtin_amdgcn_s_barrier();
  __builtin_amdgcn_sched_barrier(0);

  floatx4 zero = {0.f, 0.f, 0.f, 0.f};
  floatx4 acc[4][4];
  #pragma unroll
  for (int mt = 0; mt < 4; mt++)
    #pragma unroll
    for (int nt = 0; nt < 4; nt++) acc[mt][nt] = zero;

  for (int kt = 0; kt < KT; ++kt) {
    int c = kt & 1;
    const u16 (*Ah)[64] = As[c];
    const u16 (*Bh)[64] = Bs[c];

    short8 af[4][2], bf[4][2];

    // ---- phase 0: read all A-frags (8 ds_read) + B n0-1 (4); stage (kt+1) B0,B1 ->
    //      buf[c^1] (its readers finished last iteration); barrier; MFMA m0-3 x n0-1
    #pragma unroll
    for (int mt = 0; mt < 4; mt++)
      #pragma unroll
      for (int kk = 0; kk < 2; kk++)
        af[mt][kk] = *(const short8*)&Ah[wr * 64 + mt * 16 + l16][((kk * 4 + quad) ^ sx) << 3];
    #pragma unroll
    for (int nt = 0; nt < 2; nt++)
      #pragma unroll
      for (int kk = 0; kk < 2; kk++)
        bf[nt][kk] = *(const short8*)&Bh[wc * 64 + nt * 16 + l16][((kk * 4 + quad) ^ sx) << 3];
    STAGE(kt + 1, 2);
    STAGE(kt + 1, 3);
    __builtin_amdgcn_s_barrier();
    __builtin_amdgcn_s_setprio(1);
    #pragma unroll
    for (int nt = 0; nt < 2; nt++)
      #pragma unroll
      for (int mt = 0; mt < 4; mt++)
        #pragma unroll
        for (int kk = 0; kk < 2; kk++)
          acc[mt][nt] = __builtin_amdgcn_mfma_f32_16x16x32_bf16(af[mt][kk], bf[nt][kk], acc[mt][nt], 0, 0, 0);
    __builtin_amdgcn_s_setprio(0);
    __builtin_amdgcn_s_barrier();   // all waves' As[c] reads consumed beyond this point

    // ---- phase 1: read B n2-3 (4); stage (kt+2) A0,A1 -> buf[c] (safe after the barrier
    //      above); MFMA m0-3 x n2-3; counted vmcnt + barrier (except last iteration)
    #pragma unroll
    for (int nt = 2; nt < 4; nt++)
      #pragma unroll
      for (int kk = 0; kk < 2; kk++)
        bf[nt][kk] = *(const short8*)&Bh[wc * 64 + nt * 16 + l16][((kk * 4 + quad) ^ sx) << 3];
    STAGE(kt + 2, 0);
    STAGE(kt + 2, 1);
    __builtin_amdgcn_s_setprio(1);
    #pragma unroll
    for (int nt = 2; nt < 4; nt++)
      #pragma unroll
      for (int mt = 0; mt < 4; mt++)
        #pragma unroll
        for (int kk = 0; kk < 2; kk++)
          acc[mt][nt] = __builtin_amdgcn_mfma_f32_16x16x32_bf16(af[mt][kk], bf[nt][kk], acc[mt][nt], 0, 0, 0);
    __builtin_amdgcn_s_setprio(0);

    if (kt < KT - 1) {
      // ledger: loop-top invariant 4 outstanding [A(kt+1)]; +4 B(kt+1) ph0, +4 A(kt+2) ph1.
      // Need A(kt+1)+B(kt+1) resident -> drain 8 oldest -> vmcnt(4).
      // kt==KT-2: A(KT) was skipped (8 outstanding total) -> full drain.
      if (kt == KT - 2) asm volatile("s_waitcnt vmcnt(0)" ::: "memory");
      else              asm volatile("s_waitcnt vmcnt(4)" ::: "memory");
      __builtin_amdgcn_s_barrier();
      __builtin_amdgcn_sched_barrier(0);
    }
  }

  // epilogue (vmem queue empty): D row = quad*4+r, col = l16; wave tile 64x64 at (wr,wc)
  #pragma unroll
  for (int mt = 0; mt < 4; mt++) {
    #pragma unroll
    for (int nt = 0; nt < 4; nt++) {
      int nc = n0 + wc * 64 + nt * 16 + l16;
      float bv = bias[nc];
      #pragma unroll
      for (int r = 0; r < 4; r++) {
        int mr = m0 + wr * 64 + mt * 16 + quad * 4 + r;
        size_t idx = (size_t)mr * Nd + nc;
        float v = acc[mt][nt][r] + bv;
        if constexpr (EPI == 1) {
          ((float*)Cv)[idx] = v + resid[idx];
        } else if constexpr (EPI == 2) {
          v = 0.5f * v * (1.f + erff(v * 0.70710678118654752f));
          ((u16*)Cv)[idx] = f2b(v);
        } else {
          ((u16*)Cv)[idx] = f2b(v);
        }
      }
    }
  }
}

// ---------------- MFMA attention (RoPE fused): one block per (batch, head) ----------------
__device__ __forceinline__ int grp(int tk) { return tk == 0 ? 0 : (tk < 5 ? 1 : (tk < 21 ? 2 : 3)); }

__global__ __launch_bounds__(256) void attn_kernel(const u16* __restrict__ qkv,
    const float* __restrict__ coords, u16* __restrict__ out)
{
  __shared__ u16 Qs[96 * 72];   // [token][d], stride 72
  __shared__ u16 Ks[96 * 72];   // [token][d]
  __shared__ u16 Vt[64 * 104];  // [d][token], stride 104
  __shared__ u16 Pb[96 * 104];  // [row][col] softmax probs, bf16

  int b = blockIdx.x >> 3, h = blockIdx.x & 7;
  int tid = threadIdx.x;
  const u16* base = qkv + ((size_t)b * 85) * 1536 + h * 64;

  for (int idx = tid; idx < 96 * 64; idx += 256) {
    int tk = idx >> 6, d = idx & 63;
    float qv = 0.f, kv = 0.f; u16 vv = 0;
    if (tk < 85) {
      const u16* qp = base + (size_t)tk * 1536;
      vv = qp[1024 + d];
      if (tk == 0) {
        qv = b2f(qp[d]); kv = b2f(qp[512 + d]);
      } else {
        int j = d & 15, q4 = d >> 4;
        float coord = coords[(tk - 1) * 2 + (q4 >> 1)];
        float freq = __expf((float)j * -0.14391156831212787f);  // -ln(10)/16
        float ang = coord * freq * 6.283185307179586f;
        float sn, cs; __sincosf(ang, &sn, &cs);
        int p0 = ((q4 & 2) << 4) + j, p1 = p0 + 16;
        float a0 = b2f(qp[p0]),       a1 = b2f(qp[p1]);
        float k0 = b2f(qp[512 + p0]), k1 = b2f(qp[512 + p1]);
        if (q4 & 1) { qv = a0 * sn + a1 * cs; kv = k0 * sn + k1 * cs; }
        else        { qv = a0 * cs - a1 * sn; kv = k0 * cs - k1 * sn; }
      }
    }
    Qs[tk * 72 + d] = f2b(qv);
    Ks[tk * 72 + d] = f2b(kv);
    Vt[d * 104 + tk] = vv;
  }
  __syncthreads();

  int wave = tid >> 6, lane = tid & 63, quad = lane >> 4, l16 = lane & 15;
  const unsigned MBITS = 0x8539u;
  floatx4 zero = {0.f, 0.f, 0.f, 0.f};

  int nb = (wave < 2) ? 2 : 1;     // 6 row-bands of 16 over 4 waves: {0,4},{1,5},{2},{3}
  for (int bi = 0; bi < nb; bi++) {
    int band = (bi == 0) ? wave : wave + 4;

    // S = Q K^T (frag = 8 elems at k = quad*8 + 32*kstep)
    short8 a0 = *(const short8*)&Qs[(band * 16 + l16) * 72 + quad * 8];
    short8 a1 = *(const short8*)&Qs[(band * 16 + l16) * 72 + 32 + quad * 8];
    floatx4 s[6];
    #pragma unroll
    for (int nt = 0; nt < 6; nt++) {
      short8 b0 = *(const short8*)&Ks[(nt * 16 + l16) * 72 + quad * 8];
      short8 b1 = *(const short8*)&Ks[(nt * 16 + l16) * 72 + 32 + quad * 8];
      floatx4 tmp = __builtin_amdgcn_mfma_f32_16x16x32_bf16(a0, b0, zero, 0, 0, 0);
      s[nt] = __builtin_amdgcn_mfma_f32_16x16x32_bf16(a1, b1, tmp, 0, 0, 0);
    }

    int rb = band * 16 + quad * 4;
    #pragma unroll
    for (int r = 0; r < 4; r++) {
      int row = rb + r, gr = grp(row);
      float mx = -3.4e38f;
      #pragma unroll
      for (int nt = 0; nt < 6; nt++) {
        int col = nt * 16 + l16;
        float m = (col < 85 && ((MBITS >> (gr * 4 + grp(col))) & 1)) ? 0.f : -1e30f;
        s[nt][r] = s[nt][r] * 0.125f + m;
        mx = fmaxf(mx, s[nt][r]);
      }
      #pragma unroll
      for (int off = 1; off < 16; off <<= 1) mx = fmaxf(mx, __shfl_xor(mx, off));
      float sum = 0.f;
      #pragma unroll
      for (int nt = 0; nt < 6; nt++) { s[nt][r] = __expf(s[nt][r] - mx); sum += s[nt][r]; }
      #pragma unroll
      for (int off = 1; off < 16; off <<= 1) sum += __shfl_xor(sum, off);
      float inv = 1.f / sum;
      #pragma unroll
      for (int nt = 0; nt < 6; nt++)
        Pb[row * 104 + nt * 16 + l16] = f2b(s[nt][r] * inv);
    }

    // O = P V (in-wave LDS RAW on Pb: wave reads only rows it wrote)
    floatx4 o[4];
    #pragma unroll
    for (int nt2 = 0; nt2 < 4; nt2++) o[nt2] = zero;
    #pragma unroll
    for (int ks = 0; ks < 3; ks++) {
      short8 pa = *(const short8*)&Pb[(band * 16 + l16) * 104 + ks * 32 + quad * 8];
      #pragma unroll
      for (int nt2 = 0; nt2 < 4; nt2++) {
        short8 vb = *(const short8*)&Vt[(nt2 * 16 + l16) * 104 + ks * 32 + quad * 8];
        o[nt2] = __builtin_amdgcn_mfma_f32_16x16x32_bf16(pa, vb, o[nt2], 0, 0, 0);
      }
    }
    #pragma unroll
    for (int nt2 = 0; nt2 < 4; nt2++) {
      #pragma unroll
      for (int r = 0; r < 4; r++) {
        int row = rb + r;
        if (row < 85)
          out[((size_t)b * 85 + row) * 512 + h * 64 + nt2 * 16 + l16] = f2b(o[nt2][r]);
      }
    }
  }
}

extern "C" void kernel_launch(void* const* d_in, const int* in_sizes, int n_in,
                              void* d_out, int out_size, void* d_ws, size_t ws_size,
                              hipStream_t stream) {
  (void)in_sizes; (void)n_in; (void)out_size; (void)ws_size;
  const float* x_in   = (const float*)d_in[0];
  const float* coords = (const float*)d_in[1];
  const float* ln1_w  = (const float*)d_in[2];
  const float* ln1_b  = (const float*)d_in[3];
  const float* qkv_w  = (const float*)d_in[4];
  const float* qkv_b  = (const float*)d_in[5];
  const float* proj_w = (const float*)d_in[6];
  const float* proj_b = (const float*)d_in[7];
  const float* ln2_w  = (const float*)d_in[8];
  const float* ln2_b  = (const float*)d_in[9];
  const float* fc1_w  = (const float*)d_in[10];
  const float* fc1_b  = (const float*)d_in[11];
  const float* fc2_w  = (const float*)d_in[12];
  const float* fc2_b  = (const float*)d_in[13];
  const float* lnf_w  = (const float*)d_in[14];
  const float* lnf_b  = (const float*)d_in[15];

  float* xb = (float*)d_ws;                       // fp32 residual stream
  u16*   hb = (u16*)(xb + (size_t)MTOT * 512);    // bf16 ln/attn buffer
  u16*   qb = hb + (size_t)MTOT * 512;            // bf16 qkv / fc1 buffer
  u16*   wbuf = qb + (size_t)MTOT * 2048;         // transposed bf16 weights
  u16* wq = wbuf;
  u16* wp = wq + (size_t)6 * 512 * 1536;
  u16* w1 = wp + (size_t)6 * 512 * 512;
  u16* w2 = w1 + (size_t)6 * 512 * 2048;

  dim3 blk(256);
  transpose_conv<<<dim3(1536 / 64, 512 / 64, 6), blk, 0, stream>>>(qkv_w, wq, 512, 1536);
  transpose_conv<<<dim3(512 / 64, 512 / 64, 6), blk, 0, stream>>>(proj_w, wp, 512, 512);
  transpose_conv<<<dim3(2048 / 64, 512 / 64, 6), blk, 0, stream>>>(fc1_w, w1, 512, 2048);
  transpose_conv<<<dim3(512 / 64, 2048 / 64, 6), blk, 0, stream>>>(fc2_w, w2, 2048, 512);

  const int MT = MTOT / 128;  // 340 m-tiles
  for (int l = 0; l < 6; l++) {
    const float* xcur = (l == 0) ? x_in : xb;
    ln_kernel<0><<<MTOT / 4, blk, 0, stream>>>(xcur, ln1_w + l * 512, ln1_b + l * 512, hb);
    gemm128<0><<<12 * MT, blk, 0, stream>>>(
        hb, wq + (size_t)l * 512 * 1536, qkv_b + (size_t)l * 1536, nullptr, qb, 1536, 512, 12);
    attn_kernel<<<512 * NHEAD, blk, 0, stream>>>(qb, coords, hb);
    gemm128<1><<<4 * MT, blk, 0, stream>>>(
        hb, wp + (size_t)l * 512 * 512, proj_b + (size_t)l * 512, xcur, xb, 512, 512, 4);
    ln_kernel<0><<<MTOT / 4, blk, 0, stream>>>(xb, ln2_w + l * 512, ln2_b + l * 512, hb);
    gemm128<2><<<16 * MT, blk, 0, stream>>>(
        hb, w1 + (size_t)l * 512 * 2048, fc1_b + (size_t)l * 2048, nullptr, qb, 2048, 512, 16);
    gemm128<1><<<4 * MT, blk, 0, stream>>>(
        qb, w2 + (size_t)l * 2048 * 512, fc2_b + (size_t)l * 512, xb, xb, 512, 2048, 4);
  }
  ln_kernel<1><<<MTOT / 4, blk, 0, stream>>>(xb, lnf_w, lnf_b, d_out);
}